// Round 1
// 79.406 us; speedup vs baseline: 1.0064x; 1.0064x over previous
//
#include <hip/hip_runtime.h>
#include <math.h>

// ===========================================================================
// Full algebraic collapse of the GQHAN circuit.
//
// Previous kernel already reduced: oracle sandwich -> st[b]=cos(t_b)v_b,
// st[8+b]=-sin(t_b)v_b; final H1,H2 dropped; H3+Z3 -> X3.
//
// Key further step: the ADO (H^3, CRYs, flip, CRYs) acts ONLY on the data
// wires, identically for anc=0/1, and the measurement traces the ancilla out.
// So with B = 8x8 real ADO matrix and Q the X3 quadratic form
// (Q(y) = 2*sum_{even e} y[e]*y[e|1]):
//
//   result = Q(B(c .* v)) + Q(B(s .* v)) = v^T M' v,
//   M'_jk  = M_jk * (cos t_j cos t_k + sin t_j sin t_k),   M = B^T Q B.
//
// M' is data-independent (8x8 symmetric, 64 floats). A tiny setup kernel
// computes it once into d_ws; the hot kernel per batch element is just:
// 2x float4 load, 8 fma (||v||^2), 64 fma (matvec), 8 fma (dot), rcp, store.
// Normalization folded out as before: out = (v^T M' v) / ||v||^2.
// ===========================================================================

#define RSQRT2 0.70710678118654752440f

// 8-state (data wires only; w1=4, w2=2, w3=1) gate macros, fully unrolled.
#define HAD8(y, m) do {                                           \
    _Pragma("unroll")                                             \
    for (int e = 0; e < 8; ++e) {                                 \
      if (!(e & (m))) {                                           \
        float a_ = y[e], b_ = y[e | (m)];                         \
        y[e]       = (a_ + b_) * RSQRT2;                          \
        y[e | (m)] = (a_ - b_) * RSQRT2;                          \
      }                                                           \
    }                                                             \
  } while (0)

#define CRY8(y, cm, tm, cc, ss) do {                              \
    _Pragma("unroll")                                             \
    for (int e = 0; e < 8; ++e) {                                 \
      if ((e & (cm)) && !(e & (tm))) {                            \
        float a_ = y[e], b_ = y[e | (tm)];                        \
        y[e]        = (cc) * a_ - (ss) * b_;                      \
        y[e | (tm)] = (ss) * a_ + (cc) * b_;                      \
      }                                                           \
    }                                                             \
  } while (0)

// Full ADO on an 8-vector (final Hadamards dropped; measurement is X3 form).
#define ADO8(y) do {                                              \
    HAD8(y, 4); HAD8(y, 2); HAD8(y, 1);                           \
    CRY8(y, 4, 2, ca[0], sa[0]);                                  \
    CRY8(y, 2, 1, ca[1], sa[1]);                                  \
    CRY8(y, 1, 4, ca[2], sa[2]);                                  \
    y[0] = -y[0];                                                 \
    CRY8(y, 4, 2, ca[3], sa[3]);                                  \
    CRY8(y, 2, 1, ca[4], sa[4]);                                  \
    CRY8(y, 1, 4, ca[5], sa[5]);                                  \
  } while (0)

// --------------------------------------------------------------------------
// Setup: one block of 64 threads. Thread t = (j = t>>3, k = t&7) builds
// columns j and k of B by applying the ADO to basis vectors, then writes
// M'[j][k] = [sum_{even e} (Bj[e]Bk[e|1] + Bj[e|1]Bk[e])]
//            * (cos t_j cos t_k + sin t_j sin t_k)
// (the X3 factor 2 is folded into the symmetrized sum).
// --------------------------------------------------------------------------
__global__ __launch_bounds__(64) void gqhan_setup(
    const float* __restrict__ theta_fo,
    const float* __restrict__ theta_ado,
    float* __restrict__ Mout)
{
  int t = threadIdx.x;          // 0..63
  int j = t >> 3, k = t & 7;

  float ca[6], sa[6];
#pragma unroll
  for (int q = 0; q < 6; ++q) {
    float th = 0.5f * theta_ado[q];
    ca[q] = cosf(th);
    sa[q] = sinf(th);
  }

  float yj[8], yk[8];
#pragma unroll
  for (int e = 0; e < 8; ++e) {
    yj[e] = (e == j) ? 1.0f : 0.0f;
    yk[e] = (e == k) ? 1.0f : 0.0f;
  }
  ADO8(yj);
  ADO8(yk);

  float m = 0.0f;
#pragma unroll
  for (int e = 0; e < 8; e += 2)
    m += yj[e] * yk[e + 1] + yj[e + 1] * yk[e];

  float tj = theta_fo[j], tk = theta_fo[k];
  float w = cosf(tj) * cosf(tk) + sinf(tj) * sinf(tk);
  Mout[t] = m * w;
}

// --------------------------------------------------------------------------
// Hot kernel: one thread per batch row. out[i] = (v^T M' v) / ||v||^2.
// M' is uniform across all threads -> loads scalarize to s_load (hedged as
// broadcast float4 loads that are L1-resident if scalarization fails).
// --------------------------------------------------------------------------
__global__ __launch_bounds__(256) void gqhan_main(
    const float* __restrict__ x,
    const float* __restrict__ M,
    float* __restrict__ out, int B)
{
  int i = blockIdx.x * blockDim.x + threadIdx.x;
  if (i >= B) return;

  const float4* xp = (const float4*)(x + (size_t)i * 8u);
  float4 lo = xp[0], hi = xp[1];
  float v[8] = {lo.x, lo.y, lo.z, lo.w, hi.x, hi.y, hi.z, hi.w};

  float n2 = 0.0f;
#pragma unroll
  for (int q = 0; q < 8; ++q) n2 = fmaf(v[q], v[q], n2);

  const float4* __restrict__ M4 = (const float4*)M;
  float r = 0.0f;
#pragma unroll
  for (int row = 0; row < 8; ++row) {
    float4 m0 = M4[2 * row + 0];
    float4 m1 = M4[2 * row + 1];
    float y;
    y = m0.x * v[0];
    y = fmaf(m0.y, v[1], y);
    y = fmaf(m0.z, v[2], y);
    y = fmaf(m0.w, v[3], y);
    y = fmaf(m1.x, v[4], y);
    y = fmaf(m1.y, v[5], y);
    y = fmaf(m1.z, v[6], y);
    y = fmaf(m1.w, v[7], y);
    r = fmaf(v[row], y, r);
  }

  out[i] = r * __builtin_amdgcn_rcpf(n2);
}

extern "C" void kernel_launch(void* const* d_in, const int* in_sizes, int n_in,
                              void* d_out, int out_size, void* d_ws, size_t ws_size,
                              hipStream_t stream) {
  const float* x         = (const float*)d_in[0];
  const float* theta_fo  = (const float*)d_in[1];
  const float* theta_ado = (const float*)d_in[2];
  float* out = (float*)d_out;
  float* M   = (float*)d_ws;            // 64 floats (256 B) of workspace
  int B = in_sizes[0] / 8;

  gqhan_setup<<<1, 64, 0, stream>>>(theta_fo, theta_ado, M);

  int block = 256;
  int grid = (B + block - 1) / block;
  gqhan_main<<<grid, block, 0, stream>>>(x, M, out, B);
}